// Round 1
// baseline (877.795 us; speedup 1.0000x reference)
//
#include <hip/hip_runtime.h>
#include <math.h>

#define N_NODES  50000
#define N_EDGES  800000
#define FDIM     128
#define N_GRAPHS 500
#define NEG_SLOPE 0.2f
#define EN_TOTAL (N_EDGES + N_NODES)

static __device__ __forceinline__ float lrelu(float x) {
    return x >= 0.f ? x : NEG_SLOPE * x;
}

// ---------------- h = X @ W ; asrc = h . a_src ; adst = h . a_dst ----------------
// One wave per node. W (128x128 fp32 = 64KB) staged in LDS; x row in regs, broadcast via shfl.
__global__ __launch_bounds__(256) void gemm_attn(
    const float* __restrict__ X, const float* __restrict__ W,
    const float* __restrict__ Avs, const float* __restrict__ Avd,
    float* __restrict__ H, float* __restrict__ asrcN, float* __restrict__ adstN)
{
    __shared__ float sW[FDIM * FDIM];
    for (int i = threadIdx.x; i < FDIM * FDIM / 4; i += 256)
        ((float4*)sW)[i] = ((const float4*)W)[i];
    __syncthreads();

    const int wave = threadIdx.x >> 6, lane = threadIdx.x & 63;
    const float2 as2 = ((const float2*)Avs)[lane];
    const float2 ad2 = ((const float2*)Avd)[lane];
    const float2* sW2 = (const float2*)sW;

    for (int n = blockIdx.x * 4 + wave; n < N_NODES; n += gridDim.x * 4) {
        float2 xv = ((const float2*)X)[(size_t)n * 64 + lane];
        float acc0 = 0.f, acc1 = 0.f;
        #pragma unroll 8
        for (int k2 = 0; k2 < 64; ++k2) {
            float xk0 = __shfl(xv.x, k2);
            float xk1 = __shfl(xv.y, k2);
            float2 w0 = sW2[(2 * k2) * 64 + lane];
            float2 w1 = sW2[(2 * k2 + 1) * 64 + lane];
            acc0 += xk0 * w0.x + xk1 * w1.x;
            acc1 += xk0 * w0.y + xk1 * w1.y;
        }
        ((float2*)H)[(size_t)n * 64 + lane] = make_float2(acc0, acc1);

        float ps = acc0 * as2.x + acc1 * as2.y;
        float pd = acc0 * ad2.x + acc1 * ad2.y;
        #pragma unroll
        for (int o = 32; o; o >>= 1) {
            ps += __shfl_xor(ps, o);
            pd += __shfl_xor(pd, o);
        }
        if (lane == 0) { asrcN[n] = ps; adstN[n] = pd; }
    }
}

// ---------------- CSR build (same topology for all 3 layers) ----------------
__global__ void count_edges(const int* __restrict__ ei, int* __restrict__ cnt) {
    int i = blockIdx.x * 256 + threadIdx.x;
    if (i < EN_TOTAL) {
        int d = (i < N_EDGES) ? ei[N_EDGES + i] : (i - N_EDGES);
        atomicAdd(&cnt[d], 1);
    }
}

__global__ __launch_bounds__(1024) void scan_counts(const int* __restrict__ cnt,
                                                    int* __restrict__ off) {
    __shared__ int part[1024];
    const int tid = threadIdx.x;
    const int chunk = (N_NODES + 1023) / 1024;
    const int lo = tid * chunk;
    const int hi = min(lo + chunk, N_NODES);
    int s = 0;
    for (int i = lo; i < hi; ++i) s += cnt[i];
    part[tid] = s;
    __syncthreads();
    for (int d = 1; d < 1024; d <<= 1) {
        int v = (tid >= d) ? part[tid - d] : 0;
        __syncthreads();
        part[tid] += v;
        __syncthreads();
    }
    int run = (tid == 0) ? 0 : part[tid - 1];
    for (int i = lo; i < hi; ++i) { off[i] = run; run += cnt[i]; }
    if (tid == 1023) off[N_NODES] = run;
}

__global__ void scatter_edges(const int* __restrict__ ei, const int* __restrict__ off,
                              int* __restrict__ cur, int* __restrict__ srcs) {
    int i = blockIdx.x * 256 + threadIdx.x;
    if (i < EN_TOTAL) {
        int s, d;
        if (i < N_EDGES) { s = ei[i]; d = ei[N_EDGES + i]; }
        else             { s = d = i - N_EDGES; }
        int p = off[d] + atomicAdd(&cur[d], 1);
        srcs[p] = s;
    }
}

// ---------------- segment softmax + weighted aggregation, one wave per dst node ----------------
__global__ __launch_bounds__(256) void gat_aggregate(
    const float* __restrict__ H, const int* __restrict__ off, const int* __restrict__ srcs,
    const float* __restrict__ asrcN, const float* __restrict__ adstN,
    const float* __restrict__ bias, float* __restrict__ OUT, int doRelu)
{
    const int wave = threadIdx.x >> 6, lane = threadIdx.x & 63;
    const float2 b2 = ((const float2*)bias)[lane];
    for (int n = blockIdx.x * 4 + wave; n < N_NODES; n += gridDim.x * 4) {
        const int s0 = off[n], s1 = off[n + 1];
        const float ad = adstN[n];
        // pass 1: segment max (lane-parallel over edges)
        float m = -1e30f;
        for (int j = s0 + lane; j < s1; j += 64)
            m = fmaxf(m, lrelu(asrcN[srcs[j]] + ad));
        #pragma unroll
        for (int o = 32; o; o >>= 1) m = fmaxf(m, __shfl_xor(m, o));
        // pass 2: serial over edges; lanes own 2 features each
        float denom = 0.f, accx = 0.f, accy = 0.f;
        for (int j = s0; j < s1; ++j) {
            const int s = srcs[j];
            const float ex = __expf(lrelu(asrcN[s] + ad) - m);
            denom += ex;
            const float2 hv = ((const float2*)H)[(size_t)s * 64 + lane];
            accx += ex * hv.x;
            accy += ex * hv.y;
        }
        const float rd = 1.f / denom;
        float ox = accx * rd + b2.x;
        float oy = accy * rd + b2.y;
        if (doRelu) { ox = fmaxf(ox, 0.f); oy = fmaxf(oy, 0.f); }
        ((float2*)OUT)[(size_t)n * 64 + lane] = make_float2(ox, oy);
    }
}

// ---------------- global mean pool (batch sorted) + final linear ----------------
__global__ __launch_bounds__(128) void pool_linear(
    const float* __restrict__ H, const int* __restrict__ batch,
    const float* __restrict__ Wlin, const float* __restrict__ blin,
    float* __restrict__ out)
{
    const int g = blockIdx.x, f = threadIdx.x;
    int a = 0, b = N_NODES;
    while (a < b) { int mid = (a + b) >> 1; if (batch[mid] < g) a = mid + 1; else b = mid; }
    const int lo = a;
    b = N_NODES;
    while (a < b) { int mid = (a + b) >> 1; if (batch[mid] <= g) a = mid + 1; else b = mid; }
    const int hi = a;

    float acc = 0.f;
    for (int n = lo; n < hi; ++n) acc += H[(size_t)n * FDIM + f];
    const float pooled = acc / fmaxf((float)(hi - lo), 1.0f);

    __shared__ float red0[128], red1[128];
    red0[f] = pooled * Wlin[f * 2 + 0];
    red1[f] = pooled * Wlin[f * 2 + 1];
    __syncthreads();
    for (int st = 64; st; st >>= 1) {
        if (f < st) { red0[f] += red0[f + st]; red1[f] += red1[f + st]; }
        __syncthreads();
    }
    if (f == 0) {
        out[g * 2 + 0] = red0[0] + blin[0];
        out[g * 2 + 1] = red1[0] + blin[1];
    }
}

extern "C" void kernel_launch(void* const* d_in, const int* in_sizes, int n_in,
                              void* d_out, int out_size, void* d_ws, size_t ws_size,
                              hipStream_t stream)
{
    const float* x     = (const float*)d_in[0];
    const int*   ei    = (const int*)d_in[1];
    const int*   batch = (const int*)d_in[2];
    const float* W[3]    = {(const float*)d_in[3],  (const float*)d_in[7],  (const float*)d_in[11]};
    const float* avs[3]  = {(const float*)d_in[4],  (const float*)d_in[8],  (const float*)d_in[12]};
    const float* avd[3]  = {(const float*)d_in[5],  (const float*)d_in[9],  (const float*)d_in[13]};
    const float* bias[3] = {(const float*)d_in[6],  (const float*)d_in[10], (const float*)d_in[14]};
    const float* Wlin = (const float*)d_in[15];
    const float* blin = (const float*)d_in[16];
    float* out = (float*)d_out;

    // workspace layout (256B-aligned chunks)
    char* w = (char*)d_ws;
    float* hA    = (float*)w; w += (size_t)N_NODES * FDIM * 4;   // 25.6 MB
    float* hB    = (float*)w; w += (size_t)N_NODES * FDIM * 4;   // 25.6 MB
    float* asrcN = (float*)w; w += 200192;
    float* adstN = (float*)w; w += 200192;
    int*   off   = (int*)w;   w += 200192;                        // N+1 ints
    int*   cnt   = (int*)w;   w += 200192;                        // N ints
    int*   srcs  = (int*)w;   w += (size_t)EN_TOTAL * 4;          // 3.4 MB

    // ---- CSR by destination (topology shared across layers) ----
    hipMemsetAsync(cnt, 0, N_NODES * sizeof(int), stream);
    count_edges<<<(EN_TOTAL + 255) / 256, 256, 0, stream>>>(ei, cnt);
    scan_counts<<<1, 1024, 0, stream>>>(cnt, off);
    hipMemsetAsync(cnt, 0, N_NODES * sizeof(int), stream);
    scatter_edges<<<(EN_TOTAL + 255) / 256, 256, 0, stream>>>(ei, off, cnt, srcs);

    // ---- 3 GAT layers ----
    const float* hin = x;
    for (int l = 0; l < 3; ++l) {
        gemm_attn<<<1024, 256, 0, stream>>>(hin, W[l], avs[l], avd[l], hA, asrcN, adstN);
        gat_aggregate<<<2048, 256, 0, stream>>>(hA, off, srcs, asrcN, adstN, bias[l], hB,
                                                (l < 2) ? 1 : 0);
        hin = hB;
    }

    // ---- mean pool + linear ----
    pool_linear<<<N_GRAPHS, 128, 0, stream>>>(hB, batch, Wlin, blin, out);
}

// Round 2
// 535.573 us; speedup vs baseline: 1.6390x; 1.6390x over previous
//
#include <hip/hip_runtime.h>
#include <math.h>

#define N_NODES  50000
#define N_EDGES  800000
#define FDIM     128
#define N_GRAPHS 500
#define NEG_SLOPE 0.2f
#define EN_TOTAL (N_EDGES + N_NODES)
#define NPW 4          // nodes per wave-iteration in gemm

static __device__ __forceinline__ float lrelu(float x) {
    return x >= 0.f ? x : NEG_SLOPE * x;
}

// ---------------- h = X @ W ; asrc = h . a_src ; adst = h . a_dst ----------------
// W-stationary in registers: wave owns 64 columns (1 col/lane, wreg[128]).
// x[k] is a wave-uniform scalar load (node idx via readfirstlane) -> pure FMA loop.
// Two waves (column halves) per node stream; alpha dots combined via atomicAdd
// into a zeroed buffer.
__global__ __launch_bounds__(256) void gemm_attn(
    const float* __restrict__ X, const float* __restrict__ W,
    const float* __restrict__ Avs, const float* __restrict__ Avd,
    float* __restrict__ H, float* __restrict__ asrcN, float* __restrict__ adstN)
{
    const int w = threadIdx.x >> 6, lane = threadIdx.x & 63;
    const int colHalf = w & 1, stream = w >> 1;
    const int c = colHalf * 64 + lane;

    // persistent W column in registers (fully unrolled -> stays in VGPRs)
    float wreg[FDIM];
    #pragma unroll
    for (int k = 0; k < FDIM; ++k) wreg[k] = W[k * FDIM + c];

    const float as_c = Avs[c];
    const float ad_c = Avd[c];

    const int streamStride = gridDim.x * 2 * NPW;
    for (int base0 = (blockIdx.x * 2 + stream) * NPW; base0 < N_NODES; base0 += streamStride) {
        const int b = __builtin_amdgcn_readfirstlane(base0);
        const float* xr0 = X + (size_t)min(b + 0, N_NODES - 1) * FDIM;
        const float* xr1 = X + (size_t)min(b + 1, N_NODES - 1) * FDIM;
        const float* xr2 = X + (size_t)min(b + 2, N_NODES - 1) * FDIM;
        const float* xr3 = X + (size_t)min(b + 3, N_NODES - 1) * FDIM;

        float ac0 = 0.f, ac1 = 0.f, ac2 = 0.f, ac3 = 0.f;
        #pragma unroll
        for (int k = 0; k < FDIM; ++k) {
            const float wk = wreg[k];
            ac0 = fmaf(xr0[k], wk, ac0);
            ac1 = fmaf(xr1[k], wk, ac1);
            ac2 = fmaf(xr2[k], wk, ac2);
            ac3 = fmaf(xr3[k], wk, ac3);
        }

        // attention dot partials over this wave's 64 columns
        float p0s = ac0 * as_c, p0d = ac0 * ad_c;
        float p1s = ac1 * as_c, p1d = ac1 * ad_c;
        float p2s = ac2 * as_c, p2d = ac2 * ad_c;
        float p3s = ac3 * as_c, p3d = ac3 * ad_c;
        #pragma unroll
        for (int o = 1; o <= 32; o <<= 1) {
            p0s += __shfl_xor(p0s, o); p0d += __shfl_xor(p0d, o);
            p1s += __shfl_xor(p1s, o); p1d += __shfl_xor(p1d, o);
            p2s += __shfl_xor(p2s, o); p2d += __shfl_xor(p2d, o);
            p3s += __shfl_xor(p3s, o); p3d += __shfl_xor(p3d, o);
        }

        if (b + 0 < N_NODES) H[(size_t)(b + 0) * FDIM + c] = ac0;
        if (b + 1 < N_NODES) H[(size_t)(b + 1) * FDIM + c] = ac1;
        if (b + 2 < N_NODES) H[(size_t)(b + 2) * FDIM + c] = ac2;
        if (b + 3 < N_NODES) H[(size_t)(b + 3) * FDIM + c] = ac3;
        if (lane == 0) {
            if (b + 0 < N_NODES) { atomicAdd(&asrcN[b + 0], p0s); atomicAdd(&adstN[b + 0], p0d); }
            if (b + 1 < N_NODES) { atomicAdd(&asrcN[b + 1], p1s); atomicAdd(&adstN[b + 1], p1d); }
            if (b + 2 < N_NODES) { atomicAdd(&asrcN[b + 2], p2s); atomicAdd(&adstN[b + 2], p2d); }
            if (b + 3 < N_NODES) { atomicAdd(&asrcN[b + 3], p3s); atomicAdd(&adstN[b + 3], p3d); }
        }
    }
}

// ---------------- CSR build (same topology for all 3 layers) ----------------
__global__ void count_edges(const int* __restrict__ ei, int* __restrict__ cnt) {
    int i = blockIdx.x * 256 + threadIdx.x;
    if (i < EN_TOTAL) {
        int d = (i < N_EDGES) ? ei[N_EDGES + i] : (i - N_EDGES);
        atomicAdd(&cnt[d], 1);
    }
}

__global__ __launch_bounds__(1024) void scan_counts(const int* __restrict__ cnt,
                                                    int* __restrict__ off) {
    __shared__ int part[1024];
    const int tid = threadIdx.x;
    const int chunk = (N_NODES + 1023) / 1024;
    const int lo = tid * chunk;
    const int hi = min(lo + chunk, N_NODES);
    int s = 0;
    for (int i = lo; i < hi; ++i) s += cnt[i];
    part[tid] = s;
    __syncthreads();
    for (int d = 1; d < 1024; d <<= 1) {
        int v = (tid >= d) ? part[tid - d] : 0;
        __syncthreads();
        part[tid] += v;
        __syncthreads();
    }
    int run = (tid == 0) ? 0 : part[tid - 1];
    for (int i = lo; i < hi; ++i) { off[i] = run; run += cnt[i]; }
    if (tid == 1023) off[N_NODES] = run;
}

__global__ void scatter_edges(const int* __restrict__ ei, const int* __restrict__ off,
                              int* __restrict__ cur, int* __restrict__ srcs) {
    int i = blockIdx.x * 256 + threadIdx.x;
    if (i < EN_TOTAL) {
        int s, d;
        if (i < N_EDGES) { s = ei[i]; d = ei[N_EDGES + i]; }
        else             { s = d = i - N_EDGES; }
        int p = off[d] + atomicAdd(&cur[d], 1);
        srcs[p] = s;
    }
}

// ---------------- segment softmax + weighted aggregation ----------------
// One wave per dst node; wave split as 4 edge-groups x 16 feature-lanes
// (8 floats per lane) so 4 gathers are in flight simultaneously.
__global__ __launch_bounds__(256) void gat_aggregate(
    const float* __restrict__ H, const int* __restrict__ off, const int* __restrict__ srcs,
    const float* __restrict__ asrcN, const float* __restrict__ adstN,
    const float* __restrict__ bias, float* __restrict__ OUT, int doRelu)
{
    const int wave = threadIdx.x >> 6, lane = threadIdx.x & 63;
    const int grp = lane >> 4, fl = lane & 15;

    for (int n = blockIdx.x * 4 + wave; n < N_NODES; n += gridDim.x * 4) {
        const int s0 = off[n], s1 = off[n + 1];
        const float ad = adstN[n];

        // pass 1: segment max (all 64 lanes edge-parallel)
        float m = -1e30f;
        for (int j = s0 + lane; j < s1; j += 64)
            m = fmaxf(m, lrelu(asrcN[srcs[j]] + m * 0.f + ad));
        #pragma unroll
        for (int o = 32; o; o >>= 1) m = fmaxf(m, __shfl_xor(m, o));

        // pass 2: 4 edges in flight (one per group); lane owns 8 features
        float a0x = 0.f, a0y = 0.f, a0z = 0.f, a0w = 0.f;
        float a1x = 0.f, a1y = 0.f, a1z = 0.f, a1w = 0.f;
        float dn = 0.f;
        const float* Hf = H + (size_t)fl * 8;
        for (int j = s0 + grp; j < s1; j += 4) {
            const int s = srcs[j];
            const float ex = __expf(lrelu(asrcN[s] + ad) - m);
            dn += ex;
            const float4* hp = (const float4*)(Hf + (size_t)s * FDIM);
            const float4 h0 = hp[0];
            const float4 h1 = hp[1];
            a0x += ex * h0.x; a0y += ex * h0.y; a0z += ex * h0.z; a0w += ex * h0.w;
            a1x += ex * h1.x; a1y += ex * h1.y; a1z += ex * h1.z; a1w += ex * h1.w;
        }
        // combine the 4 groups (lanes within a group hold identical dn)
        #pragma unroll
        for (int o = 16; o <= 32; o <<= 1) {
            dn  += __shfl_xor(dn, o);
            a0x += __shfl_xor(a0x, o); a0y += __shfl_xor(a0y, o);
            a0z += __shfl_xor(a0z, o); a0w += __shfl_xor(a0w, o);
            a1x += __shfl_xor(a1x, o); a1y += __shfl_xor(a1y, o);
            a1z += __shfl_xor(a1z, o); a1w += __shfl_xor(a1w, o);
        }

        if (grp == 0) {
            const float rd = 1.f / dn;
            const float4* bp = (const float4*)(bias + fl * 8);
            float4 b0 = bp[0], b1 = bp[1];
            float4 o0, o1;
            o0.x = a0x * rd + b0.x; o0.y = a0y * rd + b0.y;
            o0.z = a0z * rd + b0.z; o0.w = a0w * rd + b0.w;
            o1.x = a1x * rd + b1.x; o1.y = a1y * rd + b1.y;
            o1.z = a1z * rd + b1.z; o1.w = a1w * rd + b1.w;
            if (doRelu) {
                o0.x = fmaxf(o0.x, 0.f); o0.y = fmaxf(o0.y, 0.f);
                o0.z = fmaxf(o0.z, 0.f); o0.w = fmaxf(o0.w, 0.f);
                o1.x = fmaxf(o1.x, 0.f); o1.y = fmaxf(o1.y, 0.f);
                o1.z = fmaxf(o1.z, 0.f); o1.w = fmaxf(o1.w, 0.f);
            }
            float4* op = (float4*)(OUT + (size_t)n * FDIM + fl * 8);
            op[0] = o0;
            op[1] = o1;
        }
    }
}

// ---------------- global mean pool (batch sorted) + final linear ----------------
__global__ __launch_bounds__(128) void pool_linear(
    const float* __restrict__ H, const int* __restrict__ batch,
    const float* __restrict__ Wlin, const float* __restrict__ blin,
    float* __restrict__ out)
{
    const int g = blockIdx.x, f = threadIdx.x;
    int a = 0, b = N_NODES;
    while (a < b) { int mid = (a + b) >> 1; if (batch[mid] < g) a = mid + 1; else b = mid; }
    const int lo = a;
    b = N_NODES;
    while (a < b) { int mid = (a + b) >> 1; if (batch[mid] <= g) a = mid + 1; else b = mid; }
    const int hi = a;

    float acc = 0.f;
    for (int n = lo; n < hi; ++n) acc += H[(size_t)n * FDIM + f];
    const float pooled = acc / fmaxf((float)(hi - lo), 1.0f);

    __shared__ float red0[128], red1[128];
    red0[f] = pooled * Wlin[f * 2 + 0];
    red1[f] = pooled * Wlin[f * 2 + 1];
    __syncthreads();
    for (int st = 64; st; st >>= 1) {
        if (f < st) { red0[f] += red0[f + st]; red1[f] += red1[f + st]; }
        __syncthreads();
    }
    if (f == 0) {
        out[g * 2 + 0] = red0[0] + blin[0];
        out[g * 2 + 1] = red1[0] + blin[1];
    }
}

extern "C" void kernel_launch(void* const* d_in, const int* in_sizes, int n_in,
                              void* d_out, int out_size, void* d_ws, size_t ws_size,
                              hipStream_t stream)
{
    const float* x     = (const float*)d_in[0];
    const int*   ei    = (const int*)d_in[1];
    const int*   batch = (const int*)d_in[2];
    const float* W[3]    = {(const float*)d_in[3],  (const float*)d_in[7],  (const float*)d_in[11]};
    const float* avs[3]  = {(const float*)d_in[4],  (const float*)d_in[8],  (const float*)d_in[12]};
    const float* avd[3]  = {(const float*)d_in[5],  (const float*)d_in[9],  (const float*)d_in[13]};
    const float* bias[3] = {(const float*)d_in[6],  (const float*)d_in[10], (const float*)d_in[14]};
    const float* Wlin = (const float*)d_in[15];
    const float* blin = (const float*)d_in[16];
    float* out = (float*)d_out;

    // workspace layout
    char* w = (char*)d_ws;
    float* hA    = (float*)w; w += (size_t)N_NODES * FDIM * 4;   // 25.6 MB
    float* hB    = (float*)w; w += (size_t)N_NODES * FDIM * 4;   // 25.6 MB
    float* attn  = (float*)w; w += 2 * 200192;                   // asrc | adst
    int*   off   = (int*)w;   w += 200192;                       // N+1 ints
    int*   cnt   = (int*)w;   w += 200192;                       // N ints
    int*   srcs  = (int*)w;   w += (size_t)EN_TOTAL * 4;         // 3.4 MB
    float* asrcN = attn;
    float* adstN = attn + N_NODES;

    // ---- CSR by destination (topology shared across layers) ----
    hipMemsetAsync(cnt, 0, N_NODES * sizeof(int), stream);
    count_edges<<<(EN_TOTAL + 255) / 256, 256, 0, stream>>>(ei, cnt);
    scan_counts<<<1, 1024, 0, stream>>>(cnt, off);
    hipMemsetAsync(cnt, 0, N_NODES * sizeof(int), stream);
    scatter_edges<<<(EN_TOTAL + 255) / 256, 256, 0, stream>>>(ei, off, cnt, srcs);

    // ---- 3 GAT layers ----
    const float* hin = x;
    for (int l = 0; l < 3; ++l) {
        hipMemsetAsync(attn, 0, 2 * N_NODES * sizeof(float), stream);
        gemm_attn<<<768, 256, 0, stream>>>(hin, W[l], avs[l], avd[l], hA, asrcN, adstN);
        gat_aggregate<<<2048, 256, 0, stream>>>(hA, off, srcs, asrcN, adstN, bias[l], hB,
                                                (l < 2) ? 1 : 0);
        hin = hB;
    }

    // ---- mean pool + linear ----
    pool_linear<<<N_GRAPHS, 128, 0, stream>>>(hB, batch, Wlin, blin, out);
}

// Round 3
// 478.829 us; speedup vs baseline: 1.8332x; 1.1185x over previous
//
#include <hip/hip_runtime.h>
#include <math.h>

#define N_NODES  50000
#define N_EDGES  800000
#define FDIM     128
#define N_GRAPHS 500
#define NEG_SLOPE 0.2f
#define EN_TOTAL (N_EDGES + N_NODES)
#define NPW 4
#define SCAN_NB ((N_NODES + 255) / 256)   // 196

static __device__ __forceinline__ float lrelu(float x) {
    return x >= 0.f ? x : NEG_SLOPE * x;
}

// ---------------- h = X @ W ; asrc = h . a_src ; adst = h . a_dst ----------------
// W-stationary in registers: wave owns 64 columns; x[k] is wave-uniform scalar load.
__global__ __launch_bounds__(256) void gemm_attn(
    const float* __restrict__ X, const float* __restrict__ W,
    const float* __restrict__ Avs, const float* __restrict__ Avd,
    float* __restrict__ H, float* __restrict__ asrcN, float* __restrict__ adstN)
{
    const int w = threadIdx.x >> 6, lane = threadIdx.x & 63;
    const int colHalf = w & 1, strm = w >> 1;
    const int c = colHalf * 64 + lane;

    float wreg[FDIM];
    #pragma unroll
    for (int k = 0; k < FDIM; ++k) wreg[k] = W[k * FDIM + c];

    const float as_c = Avs[c];
    const float ad_c = Avd[c];

    const int streamStride = gridDim.x * 2 * NPW;
    for (int base0 = (blockIdx.x * 2 + strm) * NPW; base0 < N_NODES; base0 += streamStride) {
        const int b = __builtin_amdgcn_readfirstlane(base0);
        const float* xr0 = X + (size_t)min(b + 0, N_NODES - 1) * FDIM;
        const float* xr1 = X + (size_t)min(b + 1, N_NODES - 1) * FDIM;
        const float* xr2 = X + (size_t)min(b + 2, N_NODES - 1) * FDIM;
        const float* xr3 = X + (size_t)min(b + 3, N_NODES - 1) * FDIM;

        float ac0 = 0.f, ac1 = 0.f, ac2 = 0.f, ac3 = 0.f;
        #pragma unroll
        for (int k = 0; k < FDIM; ++k) {
            const float wk = wreg[k];
            ac0 = fmaf(xr0[k], wk, ac0);
            ac1 = fmaf(xr1[k], wk, ac1);
            ac2 = fmaf(xr2[k], wk, ac2);
            ac3 = fmaf(xr3[k], wk, ac3);
        }

        float p0s = ac0 * as_c, p0d = ac0 * ad_c;
        float p1s = ac1 * as_c, p1d = ac1 * ad_c;
        float p2s = ac2 * as_c, p2d = ac2 * ad_c;
        float p3s = ac3 * as_c, p3d = ac3 * ad_c;
        #pragma unroll
        for (int o = 1; o <= 32; o <<= 1) {
            p0s += __shfl_xor(p0s, o); p0d += __shfl_xor(p0d, o);
            p1s += __shfl_xor(p1s, o); p1d += __shfl_xor(p1d, o);
            p2s += __shfl_xor(p2s, o); p2d += __shfl_xor(p2d, o);
            p3s += __shfl_xor(p3s, o); p3d += __shfl_xor(p3d, o);
        }

        if (b + 0 < N_NODES) H[(size_t)(b + 0) * FDIM + c] = ac0;
        if (b + 1 < N_NODES) H[(size_t)(b + 1) * FDIM + c] = ac1;
        if (b + 2 < N_NODES) H[(size_t)(b + 2) * FDIM + c] = ac2;
        if (b + 3 < N_NODES) H[(size_t)(b + 3) * FDIM + c] = ac3;
        if (lane == 0) {
            if (b + 0 < N_NODES) { atomicAdd(&asrcN[b + 0], p0s); atomicAdd(&adstN[b + 0], p0d); }
            if (b + 1 < N_NODES) { atomicAdd(&asrcN[b + 1], p1s); atomicAdd(&adstN[b + 1], p1d); }
            if (b + 2 < N_NODES) { atomicAdd(&asrcN[b + 2], p2s); atomicAdd(&adstN[b + 2], p2d); }
            if (b + 3 < N_NODES) { atomicAdd(&asrcN[b + 3], p3s); atomicAdd(&adstN[b + 3], p3d); }
        }
    }
}

// ---------------- CSR build ----------------
__global__ void count_edges(const int* __restrict__ ei, int* __restrict__ cnt) {
    int i = blockIdx.x * 256 + threadIdx.x;
    if (i < EN_TOTAL) {
        int d = (i < N_EDGES) ? ei[N_EDGES + i] : (i - N_EDGES);
        atomicAdd(&cnt[d], 1);
    }
}

// hierarchical scan: per-block inclusive scan -> scan of block sums -> add base
__global__ __launch_bounds__(256) void scan_block(const int* __restrict__ cnt,
                                                  int* __restrict__ off,
                                                  int* __restrict__ blockSums) {
    __shared__ int s[256];
    const int i = blockIdx.x * 256 + threadIdx.x;
    s[threadIdx.x] = (i < N_NODES) ? cnt[i] : 0;
    __syncthreads();
    #pragma unroll
    for (int d = 1; d < 256; d <<= 1) {
        int t = (threadIdx.x >= d) ? s[threadIdx.x - d] : 0;
        __syncthreads();
        s[threadIdx.x] += t;
        __syncthreads();
    }
    if (i < N_NODES) off[i + 1] = s[threadIdx.x];
    if (threadIdx.x == 255) blockSums[blockIdx.x] = s[255];
}

__global__ __launch_bounds__(256) void scan_sums(int* __restrict__ blockSums) {
    __shared__ int s[256];
    s[threadIdx.x] = (threadIdx.x < SCAN_NB) ? blockSums[threadIdx.x] : 0;
    __syncthreads();
    #pragma unroll
    for (int d = 1; d < 256; d <<= 1) {
        int t = (threadIdx.x >= d) ? s[threadIdx.x - d] : 0;
        __syncthreads();
        s[threadIdx.x] += t;
        __syncthreads();
    }
    if (threadIdx.x < SCAN_NB)
        blockSums[threadIdx.x] = (threadIdx.x == 0) ? 0 : s[threadIdx.x - 1];
}

__global__ __launch_bounds__(256) void add_base(int* __restrict__ off,
                                                const int* __restrict__ blockSums) {
    const int i = blockIdx.x * 256 + threadIdx.x;
    if (i < N_NODES) off[i + 1] += blockSums[blockIdx.x];
    if (i == 0) off[0] = 0;
}

__global__ void scatter_edges(const int* __restrict__ ei, const int* __restrict__ off,
                              int* __restrict__ cur, int* __restrict__ srcs) {
    int i = blockIdx.x * 256 + threadIdx.x;
    if (i < EN_TOTAL) {
        int s, d;
        if (i < N_EDGES) { s = ei[i]; d = ei[N_EDGES + i]; }
        else             { s = d = i - N_EDGES; }
        int p = off[d] + atomicAdd(&cur[d], 1);
        srcs[p] = s;
    }
}

// ---------------- segment softmax + weighted aggregation ----------------
// One wave per dst node. Pass 1: lane-parallel e_j + max (e kept in registers).
// Pass 2: 8 edge-groups x 8 lanes (16 floats/lane), e broadcast via shfl for deg<=64.
__global__ __launch_bounds__(256) void gat_aggregate(
    const float* __restrict__ H, const int* __restrict__ off, const int* __restrict__ srcs,
    const float* __restrict__ asrcN, const float* __restrict__ adstN,
    const float* __restrict__ bias, float* __restrict__ OUT, int doRelu)
{
    const int wave = threadIdx.x >> 6, lane = threadIdx.x & 63;
    const int grp = lane >> 3, fl = lane & 7;

    for (int n = blockIdx.x * 4 + wave; n < N_NODES; n += gridDim.x * 4) {
        const int s0 = off[n], s1 = off[n + 1];
        const int deg = s1 - s0;
        const float ad = adstN[n];

        // pass 1: per-edge logits, lane-parallel; keep first 64 in registers
        float e_reg = -1e30f;
        float m = -1e30f;
        for (int j = s0 + lane; j < s1; j += 64) {
            float e = lrelu(asrcN[srcs[j]] + ad);
            if (j - s0 < 64) e_reg = e;
            m = fmaxf(m, e);
        }
        #pragma unroll
        for (int o = 32; o; o >>= 1) m = fmaxf(m, __shfl_xor(m, o));

        // pass 2: 8 edges in flight; lane owns 16 features
        float4 a0 = {0,0,0,0}, a1 = {0,0,0,0}, a2 = {0,0,0,0}, a3 = {0,0,0,0};
        float dn = 0.f;
        const float* Hf = H + (size_t)fl * 16;
        if (deg <= 64) {
            for (int j = s0 + grp; j < s1; j += 8) {
                const int s = srcs[j];
                const float ex = __expf(__shfl(e_reg, j - s0) - m);
                dn += ex;
                const float4* hp = (const float4*)(Hf + (size_t)s * FDIM);
                const float4 h0 = hp[0], h1 = hp[1], h2 = hp[2], h3 = hp[3];
                a0.x += ex*h0.x; a0.y += ex*h0.y; a0.z += ex*h0.z; a0.w += ex*h0.w;
                a1.x += ex*h1.x; a1.y += ex*h1.y; a1.z += ex*h1.z; a1.w += ex*h1.w;
                a2.x += ex*h2.x; a2.y += ex*h2.y; a2.z += ex*h2.z; a2.w += ex*h2.w;
                a3.x += ex*h3.x; a3.y += ex*h3.y; a3.z += ex*h3.z; a3.w += ex*h3.w;
            }
        } else {
            for (int j = s0 + grp; j < s1; j += 8) {
                const int s = srcs[j];
                const float ex = __expf(lrelu(asrcN[s] + ad) - m);
                dn += ex;
                const float4* hp = (const float4*)(Hf + (size_t)s * FDIM);
                const float4 h0 = hp[0], h1 = hp[1], h2 = hp[2], h3 = hp[3];
                a0.x += ex*h0.x; a0.y += ex*h0.y; a0.z += ex*h0.z; a0.w += ex*h0.w;
                a1.x += ex*h1.x; a1.y += ex*h1.y; a1.z += ex*h1.z; a1.w += ex*h1.w;
                a2.x += ex*h2.x; a2.y += ex*h2.y; a2.z += ex*h2.z; a2.w += ex*h2.w;
                a3.x += ex*h3.x; a3.y += ex*h3.y; a3.z += ex*h3.z; a3.w += ex*h3.w;
            }
        }

        // combine the 8 groups (grp = lane bits 3..5)
        #pragma unroll
        for (int o = 8; o <= 32; o <<= 1) {
            dn  += __shfl_xor(dn, o);
            a0.x += __shfl_xor(a0.x, o); a0.y += __shfl_xor(a0.y, o);
            a0.z += __shfl_xor(a0.z, o); a0.w += __shfl_xor(a0.w, o);
            a1.x += __shfl_xor(a1.x, o); a1.y += __shfl_xor(a1.y, o);
            a1.z += __shfl_xor(a1.z, o); a1.w += __shfl_xor(a1.w, o);
            a2.x += __shfl_xor(a2.x, o); a2.y += __shfl_xor(a2.y, o);
            a2.z += __shfl_xor(a2.z, o); a2.w += __shfl_xor(a2.w, o);
            a3.x += __shfl_xor(a3.x, o); a3.y += __shfl_xor(a3.y, o);
            a3.z += __shfl_xor(a3.z, o); a3.w += __shfl_xor(a3.w, o);
        }

        if (grp == 0) {
            const float rd = 1.f / dn;
            const float4* bp = (const float4*)(bias + fl * 16);
            float4 ov[4] = {a0, a1, a2, a3};
            float4* op = (float4*)(OUT + (size_t)n * FDIM + fl * 16);
            #pragma unroll
            for (int q = 0; q < 4; ++q) {
                float4 b4 = bp[q];
                float4 o4;
                o4.x = ov[q].x * rd + b4.x; o4.y = ov[q].y * rd + b4.y;
                o4.z = ov[q].z * rd + b4.z; o4.w = ov[q].w * rd + b4.w;
                if (doRelu) {
                    o4.x = fmaxf(o4.x, 0.f); o4.y = fmaxf(o4.y, 0.f);
                    o4.z = fmaxf(o4.z, 0.f); o4.w = fmaxf(o4.w, 0.f);
                }
                op[q] = o4;
            }
        }
    }
}

// ---------------- global mean pool (batch sorted) + final linear ----------------
__global__ __launch_bounds__(128) void pool_linear(
    const float* __restrict__ H, const int* __restrict__ batch,
    const float* __restrict__ Wlin, const float* __restrict__ blin,
    float* __restrict__ out)
{
    const int g = blockIdx.x, f = threadIdx.x;
    int a = 0, b = N_NODES;
    while (a < b) { int mid = (a + b) >> 1; if (batch[mid] < g) a = mid + 1; else b = mid; }
    const int lo = a;
    b = N_NODES;
    while (a < b) { int mid = (a + b) >> 1; if (batch[mid] <= g) a = mid + 1; else b = mid; }
    const int hi = a;

    float acc = 0.f;
    for (int n = lo; n < hi; ++n) acc += H[(size_t)n * FDIM + f];
    const float pooled = acc / fmaxf((float)(hi - lo), 1.0f);

    __shared__ float red0[128], red1[128];
    red0[f] = pooled * Wlin[f * 2 + 0];
    red1[f] = pooled * Wlin[f * 2 + 1];
    __syncthreads();
    for (int st = 64; st; st >>= 1) {
        if (f < st) { red0[f] += red0[f + st]; red1[f] += red1[f + st]; }
        __syncthreads();
    }
    if (f == 0) {
        out[g * 2 + 0] = red0[0] + blin[0];
        out[g * 2 + 1] = red1[0] + blin[1];
    }
}

extern "C" void kernel_launch(void* const* d_in, const int* in_sizes, int n_in,
                              void* d_out, int out_size, void* d_ws, size_t ws_size,
                              hipStream_t stream)
{
    const float* x     = (const float*)d_in[0];
    const int*   ei    = (const int*)d_in[1];
    const int*   batch = (const int*)d_in[2];
    const float* W[3]    = {(const float*)d_in[3],  (const float*)d_in[7],  (const float*)d_in[11]};
    const float* avs[3]  = {(const float*)d_in[4],  (const float*)d_in[8],  (const float*)d_in[12]};
    const float* avd[3]  = {(const float*)d_in[5],  (const float*)d_in[9],  (const float*)d_in[13]};
    const float* bias[3] = {(const float*)d_in[6],  (const float*)d_in[10], (const float*)d_in[14]};
    const float* Wlin = (const float*)d_in[15];
    const float* blin = (const float*)d_in[16];
    float* out = (float*)d_out;

    char* w = (char*)d_ws;
    float* hA    = (float*)w; w += (size_t)N_NODES * FDIM * 4;
    float* hB    = (float*)w; w += (size_t)N_NODES * FDIM * 4;
    float* attn  = (float*)w; w += 2 * 200192;
    int*   off   = (int*)w;   w += 200192;
    int*   cnt   = (int*)w;   w += 200192;
    int*   bsum  = (int*)w;   w += 4096;
    int*   srcs  = (int*)w;   w += (size_t)EN_TOTAL * 4;
    float* asrcN = attn;
    float* adstN = attn + N_NODES;

    // ---- CSR by destination ----
    hipMemsetAsync(cnt, 0, N_NODES * sizeof(int), stream);
    count_edges<<<(EN_TOTAL + 255) / 256, 256, 0, stream>>>(ei, cnt);
    scan_block<<<SCAN_NB, 256, 0, stream>>>(cnt, off, bsum);
    scan_sums<<<1, 256, 0, stream>>>(bsum);
    add_base<<<SCAN_NB, 256, 0, stream>>>(off, bsum);
    hipMemsetAsync(cnt, 0, N_NODES * sizeof(int), stream);
    scatter_edges<<<(EN_TOTAL + 255) / 256, 256, 0, stream>>>(ei, off, cnt, srcs);

    // ---- 3 GAT layers ----
    const float* hin = x;
    for (int l = 0; l < 3; ++l) {
        hipMemsetAsync(attn, 0, 2 * N_NODES * sizeof(float), stream);
        gemm_attn<<<768, 256, 0, stream>>>(hin, W[l], avs[l], avd[l], hA, asrcN, adstN);
        gat_aggregate<<<2048, 256, 0, stream>>>(hA, off, srcs, asrcN, adstN, bias[l], hB,
                                                (l < 2) ? 1 : 0);
        hin = hB;
    }

    // ---- mean pool + linear ----
    pool_linear<<<N_GRAPHS, 128, 0, stream>>>(hB, batch, Wlin, blin, out);
}